// Round 3
// baseline (1173.439 us; speedup 1.0000x reference)
//
#include <hip/hip_runtime.h>

typedef float v16f __attribute__((ext_vector_type(16)));
typedef int   v8i  __attribute__((ext_vector_type(8)));
typedef int   v4i  __attribute__((ext_vector_type(4)));

#define BM 256
#define BN 256
#define SC1 0x7F7F7FFu + 0x7F000000u  // not used; see SCONE below

static constexpr unsigned SCONE = 0x7F7F7F7Fu;   // E8M0 scale = 1.0 in all 4 bytes

// ---------- fp8 pack helper: 4 f32 -> 4 e4m3 bytes (RNE, HW cvt) ----------
__device__ __forceinline__ unsigned int pack4_fp8(float a, float b, float c, float d) {
    unsigned int v = __builtin_amdgcn_cvt_pk_fp8_f32(a, b, 0, false);   // bytes 0,1
    v = __builtin_amdgcn_cvt_pk_fp8_f32(c, d, v, true);                 // bytes 2,3
    return v;
}

// ---------- 1) quantize input: f32 [M,K] -> e4m3 bytes [M,K] ----------
__global__ __launch_bounds__(256) void quant_x_kernel(
    const float* __restrict__ X, const float* __restrict__ sp,
    unsigned int* __restrict__ Q)
{
    const long i = (long)blockIdx.x * 256 + threadIdx.x;
    const float s = sp[0];
    const float4 v = ((const float4*)X)[i];
    const float a = fminf(fmaxf(v.x / s, -448.f), 448.f);
    const float b = fminf(fmaxf(v.y / s, -448.f), 448.f);
    const float c = fminf(fmaxf(v.z / s, -448.f), 448.f);
    const float d = fminf(fmaxf(v.w / s, -448.f), 448.f);
    Q[i] = pack4_fp8(a, b, c, d);
}

// ---------- 2) weight transpose-quant via LDS (coalesced both sides) ----------
// old version read W[K,N] with 16-row-strided 64B segments (<1 TB/s). Now:
// coalesced float4 row reads -> padded LDS [64][68] f32 -> conflict-free column
// reads -> pack4 -> contiguous uint4 stores to Wq[N,K].
__global__ __launch_bounds__(256) void quant_wT_kernel(
    const float* __restrict__ Wf, unsigned char* __restrict__ Wq, int K, int N)
{
    __shared__ float T[64][68];             // pad 68: col reads conflict-free, 16B-aligned rows
    const int tid = threadIdx.x;
    const int k0 = blockIdx.x * 64;
    const int n0 = blockIdx.y * 64;
    const int rr = tid >> 4;                // 0..15
    const int cc = (tid & 15) * 4;          // 0..60
#pragma unroll
    for (int j = 0; j < 4; ++j) {
        const int r = j * 16 + rr;
        const float4 v = *(const float4*)(Wf + (long)(k0 + r) * N + n0 + cc);
        T[r][cc + 0] = v.x; T[r][cc + 1] = v.y; T[r][cc + 2] = v.z; T[r][cc + 3] = v.w;
    }
    __syncthreads();
    const int n  = tid >> 2;                // output row (col of W)
    const int kc = (tid & 3) * 16;          // 16 k-bytes per thread
    unsigned int o[4];
#pragma unroll
    for (int q = 0; q < 4; ++q)
        o[q] = pack4_fp8(T[kc + q*4 + 0][n], T[kc + q*4 + 1][n],
                         T[kc + q*4 + 2][n], T[kc + q*4 + 3][n]);   // exact: fp8-grid values
    uint4 out; out.x = o[0]; out.y = o[1]; out.z = o[2]; out.w = o[3];
    *(uint4*)(Wq + (long)(n0 + n) * K + k0 + kc) = out;
}

// ---------- async 16B global -> LDS ----------
__device__ __forceinline__ void async_copy16(const void* g, void* l) {
    __builtin_amdgcn_global_load_lds(
        (const __attribute__((address_space(1))) unsigned int*)g,
        (__attribute__((address_space(3))) unsigned int*)l,
        16, 0, 0);
}

__device__ __forceinline__ v8i ld32(const unsigned char* p, int o0, int o1) {
    const v4i lo = *(const v4i*)(p + o0);
    const v4i hi = *(const v4i*)(p + o1);
    v8i f; f[0]=lo[0]; f[1]=lo[1]; f[2]=lo[2]; f[3]=lo[3];
           f[4]=hi[0]; f[5]=hi[1]; f[6]=hi[2]; f[7]=hi[3];
    return f;
}

// ---------- 3) fp8 GEMM: 8-phase counted-vmcnt schedule (m201 template, MX MFMA) ----
// C[M,N] = (A8[M,K] . B8[N,K]^T) * s + bias.  256x256 tile, 512 thr = 8 waves 2(M)x4(N),
// wave tile 128x64 = acc[4][2] of 32x32; mfma_scale_f32_32x32x64_f8f6f4, unit scales.
// LDS: 2 buffers x (A 32KB + B 32KB) = 128 KB; K-tile = 128 B of K.
// Iteration = 2 K-tiles = 8 phases. Phase p: quadrant q=(p&3): qm=q>>1, qn=q&1;
//   reads buf[p>>2]'s A-frags (2 mt x 2 ks) + B-frags (2 ks) = 12 ds_read_b128,
//   stages 1 unit (2 global_load_lds, 16 KB), barrier, lgkmcnt(0), 4 MFMA, barrier.
// Stage schedule (unit staged one phase after its region's last read; content tile in ()):
//   p0:A1qm1(2t+1) p1:B1qn1(2t+1) p2:A0qm0(2t+2) p3:B0qn0(2t+2)
//   p4:A0qm1(2t+2) p5:B0qn1(2t+2) p6:A1qm0(2t+3) p7:B1qn0(2t+3)
// vmcnt(4) ONLY at p3 (confirms buf1 = p6,p7 prev + p0,p1) and p7 (confirms buf0 =
// p2..p5) -- placed after MFMA, before the ending barrier; never 0 in steady state.
// Swizzle: LDS row r chunk c stored at slot c ^ (r&7); inverse applied on the GLOBAL
// source address at stage time (linear global_load_lds dest, rule 21). ds_read_b128
// fragment reads then hit the 8-cycle wave64 bank floor.
__global__ __launch_bounds__(512, 2) void fp8_gemm_kernel(
    const unsigned char* __restrict__ A8,   // [M,K] e4m3
    const unsigned char* __restrict__ B8,   // [N,K] e4m3 (pre-transposed)
    const float* __restrict__ bias,
    const float* __restrict__ ws_p, const float* __restrict__ is_p,
    float* __restrict__ C, int M, int N, int K)
{
    __shared__ unsigned char AsB[2 * 32768];   // 64 KB: [buf][256 rows][128 B]
    __shared__ unsigned char BsB[2 * 32768];   // 64 KB

    const int tid = threadIdx.x;
    const int l   = tid & 63;
    const int w   = tid >> 6;               // 0..7
    const int wr  = w >> 2, wc = w & 3;     // 2(M) x 4(N)
    const int lrow = l & 31;
    const int h    = l >> 5;
    const int sw   = lrow & 7;

    // ---- XCD-aware block swizzle (grid 43x32 = 1376, %8==0 -> bijective) ----
    int bx = blockIdx.x, by = blockIdx.y;
    {
        const int gx = gridDim.x, nwg = gridDim.x * gridDim.y;
        if ((nwg & 7) == 0) {
            const int id  = by * gx + bx;
            const int cpx = nwg >> 3;
            const int swz = (id & 7) * cpx + (id >> 3);
            bx = swz % gx;
            by = swz / gx;
        }
    }
    const long m0 = (long)by * BM;
    const long n0 = (long)bx * BN;

    // ---- staging constants ----
    const int  chOff = (((tid & 7) ^ ((tid >> 3) & 7)) << 4);   // inverse slot swizzle
    const long K64  = (long)64  * K;
    const long K32  = (long)32  * K;
    const long K128 = (long)128 * K;
    const unsigned char* aSrc = A8 + (m0 + (tid >> 3)) * (long)K + chOff;
    const unsigned char* bSrc = B8 + (n0 + (tid >> 8) * 64 + ((tid >> 3) & 31)) * (long)K + chOff;
    const int bDst = (tid >> 8) * 8192 + ((tid >> 3) & 31) * 128 + (tid & 7) * 16;

    unsigned char* As0 = AsB;          unsigned char* As1 = AsB + 32768;
    unsigned char* Bs0 = BsB;          unsigned char* Bs1 = BsB + 32768;

    // ---- per-lane ds_read constants ----
    const int aRdBase = (wr * 128 + lrow) * 128;
    const int bRdBase = (wc * 64  + lrow) * 128;
    const int c00 = (((0 + h*2 + 0) ^ sw) << 4);   // ks=0 chunks
    const int c01 = (((0 + h*2 + 1) ^ sw) << 4);
    const int c10 = (((4 + h*2 + 0) ^ sw) << 4);   // ks=1 chunks
    const int c11 = (((4 + h*2 + 1) ^ sw) << 4);

    v16f acc[4][2];
#pragma unroll
    for (int i = 0; i < 4; ++i)
#pragma unroll
        for (int j = 0; j < 2; ++j)
#pragma unroll
            for (int e = 0; e < 16; ++e)
                acc[i][j][e] = 0.f;

#define STAGE_A(DSTBASE, QM, TBYTE) do { \
    const unsigned char* s_ = aSrc + (TBYTE) + (QM) * K64; \
    async_copy16(s_,        (DSTBASE) + (QM) * 8192 + tid * 16); \
    async_copy16(s_ + K128, (DSTBASE) + 16384 + (QM) * 8192 + tid * 16); \
} while (0)

#define STAGE_B(DSTBASE, QN, TBYTE) do { \
    const unsigned char* s_ = bSrc + (TBYTE) + (QN) * K32; \
    async_copy16(s_,        (DSTBASE) + (QN) * 4096 + bDst); \
    async_copy16(s_ + K128, (DSTBASE) + 16384 + (QN) * 4096 + bDst); \
} while (0)

#define MFMA(AV, BV, D) \
    D = __builtin_amdgcn_mfma_scale_f32_32x32x64_f8f6f4( \
        (AV), (BV), (D), 0, 0, 0, SCONE, 0, SCONE)

#define PHASE(ABUF, BBUF, QM, QN, STAGE_CODE, WAIT_CODE) do { \
    const unsigned char* Ab_ = (ABUF); \
    const unsigned char* Bb_ = (BBUF); \
    const v8i a0k0 = ld32(Ab_ + aRdBase + (QM)*8192,        c00, c01); \
    const v8i a0k1 = ld32(Ab_ + aRdBase + (QM)*8192,        c10, c11); \
    const v8i a1k0 = ld32(Ab_ + aRdBase + (QM)*8192 + 4096, c00, c01); \
    const v8i a1k1 = ld32(Ab_ + aRdBase + (QM)*8192 + 4096, c10, c11); \
    const v8i b0   = ld32(Bb_ + bRdBase + (QN)*4096,        c00, c01); \
    const v8i b1   = ld32(Bb_ + bRdBase + (QN)*4096,        c10, c11); \
    STAGE_CODE; \
    __builtin_amdgcn_s_barrier(); \
    asm volatile("s_waitcnt lgkmcnt(0)" ::: "memory"); \
    __builtin_amdgcn_sched_barrier(0); \
    __builtin_amdgcn_s_setprio(1); \
    MFMA(a0k0, b0, acc[(QM)*2 + 0][QN]); \
    MFMA(a1k0, b0, acc[(QM)*2 + 1][QN]); \
    MFMA(a0k1, b1, acc[(QM)*2 + 0][QN]); \
    MFMA(a1k1, b1, acc[(QM)*2 + 1][QN]); \
    __builtin_amdgcn_s_setprio(0); \
    __builtin_amdgcn_sched_barrier(0); \
    WAIT_CODE; \
    __builtin_amdgcn_s_barrier(); \
    __builtin_amdgcn_sched_barrier(0); \
} while (0)

    // ---- prologue: tile0 -> buf0 (4 units), tile1 partial -> buf1 (Aqm0, Bqn0) ----
    STAGE_A(As0, 0, 0);   STAGE_B(Bs0, 0, 0);
    STAGE_A(As0, 1, 0);   STAGE_B(Bs0, 1, 0);
    STAGE_A(As1, 0, 128); STAGE_B(Bs1, 0, 128);
    asm volatile("s_waitcnt vmcnt(4)" ::: "memory");   // buf0 complete; tile1-partial in flight
    __builtin_amdgcn_s_barrier();

    const int NIT = K >> 8;                  // K/256: 2 K-tiles (2x128B) per iteration
    for (int it = 0; it < NIT; ++it) {
        const long tB = (long)it << 8;       // byte offset of this iteration's tile pair
        const bool lst = (it == NIT - 1);

        PHASE(As0, Bs0, 0, 0, { STAGE_A(As1, 1, tB + 128); }, {});
        PHASE(As0, Bs0, 0, 1, { STAGE_B(Bs1, 1, tB + 128); }, {});
        PHASE(As0, Bs0, 1, 0, { if (!lst) STAGE_A(As0, 0, tB + 256); }, {});
        PHASE(As0, Bs0, 1, 1, { if (!lst) STAGE_B(Bs0, 0, tB + 256); },
              { if (!lst) { asm volatile("s_waitcnt vmcnt(4)" ::: "memory"); }
                else      { asm volatile("s_waitcnt vmcnt(0)" ::: "memory"); } });
        PHASE(As1, Bs1, 0, 0, { if (!lst) STAGE_A(As0, 1, tB + 256); }, {});
        PHASE(As1, Bs1, 0, 1, { if (!lst) STAGE_B(Bs0, 1, tB + 256); }, {});
        PHASE(As1, Bs1, 1, 0, { if (!lst) STAGE_A(As1, 0, tB + 384); }, {});
        PHASE(As1, Bs1, 1, 1, { if (!lst) STAGE_B(Bs1, 0, tB + 384); },
              { if (!lst) { asm volatile("s_waitcnt vmcnt(4)" ::: "memory"); } });
    }

#undef PHASE
#undef MFMA
#undef STAGE_A
#undef STAGE_B

    // ---- epilogue: 32x32 C/D layout: col = l&31, row = (reg&3) + 8*(reg>>2) + 4*h ----
    const float s = is_p[0] * ws_p[0];
#pragma unroll
    for (int mt = 0; mt < 4; ++mt)
#pragma unroll
        for (int nt = 0; nt < 2; ++nt) {
            const long cc = n0 + wc * 64 + nt * 32 + lrow;
            const float bv = bias[cc];
            float* dst = C + (m0 + wr * 128 + mt * 32 + h * 4) * (long)N + cc;
#pragma unroll
            for (int g = 0; g < 4; ++g)
#pragma unroll
                for (int r = 0; r < 4; ++r)
                    dst[(long)(g * 8 + r) * N] = acc[mt][nt][g * 4 + r] * s + bv;
        }
}

extern "C" void kernel_launch(void* const* d_in, const int* in_sizes, int n_in,
                              void* d_out, int out_size, void* d_ws, size_t ws_size,
                              hipStream_t stream)
{
    const float* X    = (const float*)d_in[0];   // [M,K] f32
    const float* Wf   = (const float*)d_in[1];   // [K,N] f32 (fp8-grid values)
    const float* bias = (const float*)d_in[2];   // [N] f32
    const float* wsc  = (const float*)d_in[3];   // weight_scale
    const float* isc  = (const float*)d_in[4];   // input_scale
    float* out = (float*)d_out;

    const int N = in_sizes[2];
    const int K = in_sizes[1] / N;
    const int M = in_sizes[0] / K;

    unsigned char* A8 = (unsigned char*)d_ws;            // M*K bytes
    unsigned char* B8 = A8 + (size_t)M * K;              // N*K bytes

    // 1) input quant
    quant_x_kernel<<<dim3((unsigned)((long)M * K / 4 / 256)), 256, 0, stream>>>(
        X, isc, (unsigned int*)A8);

    // 2) weight quant + transpose (LDS transpose, coalesced)
    quant_wT_kernel<<<dim3(K / 64, N / 64), 256, 0, stream>>>(Wf, B8, K, N);

    // 3) GEMM + scale + bias (MX-scaled fp8, 8-phase schedule)
    fp8_gemm_kernel<<<dim3(N / BN, M / BM), 512, 0, stream>>>(
        A8, B8, bias, wsc, isc, out, M, N, K);
}

// Round 4
// 1009.698 us; speedup vs baseline: 1.1622x; 1.1622x over previous
//
#include <hip/hip_runtime.h>

typedef float v16f __attribute__((ext_vector_type(16)));
typedef int   v8i  __attribute__((ext_vector_type(8)));
typedef int   v4i  __attribute__((ext_vector_type(4)));

#define BM 256
#define BN 256
#define BKB 128                      // K-bytes staged per step
#define TILE_BYTES 32768             // 256 rows x 128 B (per matrix, per buffer)

static constexpr unsigned SCONE = 0x7F7F7F7Fu;   // E8M0 scale = 1.0 in all 4 bytes

// ---------- fp8 pack helper: 4 f32 -> 4 e4m3 bytes (RNE, HW cvt) ----------
__device__ __forceinline__ unsigned int pack4_fp8(float a, float b, float c, float d) {
    unsigned int v = __builtin_amdgcn_cvt_pk_fp8_f32(a, b, 0, false);   // bytes 0,1
    v = __builtin_amdgcn_cvt_pk_fp8_f32(c, d, v, true);                 // bytes 2,3
    return v;
}

// ---------- 1) quantize input: f32 [M,K] -> e4m3 bytes [M,K] ----------
__global__ __launch_bounds__(256) void quant_x_kernel(
    const float* __restrict__ X, const float* __restrict__ sp,
    unsigned int* __restrict__ Q)
{
    const long i = (long)blockIdx.x * 256 + threadIdx.x;
    const float s = sp[0];
    const float4 v = ((const float4*)X)[i];
    const float a = fminf(fmaxf(v.x / s, -448.f), 448.f);
    const float b = fminf(fmaxf(v.y / s, -448.f), 448.f);
    const float c = fminf(fmaxf(v.z / s, -448.f), 448.f);
    const float d = fminf(fmaxf(v.w / s, -448.f), 448.f);
    Q[i] = pack4_fp8(a, b, c, d);
}

// ---------- 2) weight transpose-quant via LDS (coalesced both sides) ----------
__global__ __launch_bounds__(256) void quant_wT_kernel(
    const float* __restrict__ Wf, unsigned char* __restrict__ Wq, int K, int N)
{
    __shared__ float T[64][68];             // pad 68: column reads conflict-free
    const int tid = threadIdx.x;
    const int k0 = blockIdx.x * 64;
    const int n0 = blockIdx.y * 64;
    const int rr = tid >> 4;                // 0..15
    const int cc = (tid & 15) * 4;          // 0..60
#pragma unroll
    for (int j = 0; j < 4; ++j) {
        const int r = j * 16 + rr;
        const float4 v = *(const float4*)(Wf + (long)(k0 + r) * N + n0 + cc);
        T[r][cc + 0] = v.x; T[r][cc + 1] = v.y; T[r][cc + 2] = v.z; T[r][cc + 3] = v.w;
    }
    __syncthreads();
    const int n  = tid >> 2;                // output row (col of W)
    const int kc = (tid & 3) * 16;          // 16 k-bytes per thread
    unsigned int o[4];
#pragma unroll
    for (int q = 0; q < 4; ++q)
        o[q] = pack4_fp8(T[kc + q*4 + 0][n], T[kc + q*4 + 1][n],
                         T[kc + q*4 + 2][n], T[kc + q*4 + 3][n]);   // exact: fp8-grid values
    uint4 out; out.x = o[0]; out.y = o[1]; out.z = o[2]; out.w = o[3];
    *(uint4*)(Wq + (long)(n0 + n) * K + k0 + kc) = out;
}

// ---------- async 16B global -> LDS ----------
__device__ __forceinline__ void async_copy16(const void* g, void* l) {
    __builtin_amdgcn_global_load_lds(
        (const __attribute__((address_space(1))) unsigned int*)g,
        (__attribute__((address_space(3))) unsigned int*)l,
        16, 0, 0);
}

__device__ __forceinline__ v8i ld32(const unsigned char* p, int o0, int o1) {
    const v4i lo = *(const v4i*)(p + o0);
    const v4i hi = *(const v4i*)(p + o1);
    v8i f; f[0]=lo[0]; f[1]=lo[1]; f[2]=lo[2]; f[3]=lo[3];
           f[4]=hi[0]; f[5]=hi[1]; f[6]=hi[2]; f[7]=hi[3];
    return f;
}

// ---------- 3) fp8 GEMM: fat-wave MX schedule ----------
// C[M,N] = (A8[M,K] . B8[N,K]^T) * s + bias.
// 256x256 block tile, 256 threads = 4 waves in 2x2; EACH WAVE owns 128x128
// (acc[4][4] of 32x32 = 256 f32 -> needs the full 512-reg/wave budget:
// __launch_bounds__(256,1). Round-3 lesson: (512,2) caps at 256 regs -> spills
// -> +645 MB HBM scratch traffic).
// Rationale vs round 2/3: at MX rates LDS-read BW is the wall. Per 128B K-step
// per CU: matrix = 32 MFMA x 4 waves x 17.2cy = 2200 cy; LDS frag reads =
// 4 waves x 16 ds_read_b128 = 64 KB = ~520 cy (+conflicts ~1.6x) -- first
// schedule where matrix dominates. Read-once per step (no quadrant re-reads).
// Pipeline: 2 LDS buffers, depth-1 prefetch, counted vmcnt(16) (never 0
// in-loop); 2 raw barriers per 128B step; MFMA drain (2200cy) hides reads,
// staging, and barrier latency. No setprio (1 wave/SIMD), no manual lgkm
// (compiler emits fine-grained lgkmcnt for ds_read->MFMA).
// LDS swizzle: row r (128 B = 8 x 16B slots), chunk c stored at slot c ^ (r&7);
// inverse applied on GLOBAL source address (linear global_load_lds dest, rule 21).
__global__ __launch_bounds__(256, 1) void fp8_gemm_kernel(
    const unsigned char* __restrict__ A8,   // [M,K] e4m3
    const unsigned char* __restrict__ B8,   // [N,K] e4m3 (pre-transposed)
    const float* __restrict__ bias,
    const float* __restrict__ ws_p, const float* __restrict__ is_p,
    float* __restrict__ C, int M, int N, int K)
{
    __shared__ unsigned char AsB[2 * TILE_BYTES];   // 64 KB
    __shared__ unsigned char BsB[2 * TILE_BYTES];   // 64 KB

    const int tid = threadIdx.x;
    const int l   = tid & 63;
    const int w   = tid >> 6;               // 0..3
    const int wr  = w >> 1, wc = w & 1;     // 2x2 wave grid, wave tile 128x128
    const int lrow = l & 31;
    const int h    = l >> 5;
    const int sw   = lrow & 7;

    // ---- XCD-aware block swizzle (grid 43x32 = 1376, %8==0 -> bijective) ----
    int bx = blockIdx.x, by = blockIdx.y;
    {
        const int gx = gridDim.x, nwg = gridDim.x * gridDim.y;
        if ((nwg & 7) == 0) {
            const int id  = by * gx + bx;
            const int cpx = nwg >> 3;
            const int swz = (id & 7) * cpx + (id >> 3);
            bx = swz % gx;
            by = swz / gx;
        }
    }
    const long m0 = (long)by * BM;
    const long n0 = (long)bx * BN;

    // ---- staging: thread covers row (tid>>3)+32j, chunk tid&7; 8 issues per matrix
    // LDS dst = base + tid*16 + j*4096 (linear); global chunk inverse-swizzled.
    const int  chOff = (((tid & 7) ^ ((tid >> 3) & 7)) << 4);
    const long rowStep = (long)32 * K;
    const unsigned char* aSrc = A8 + (m0 + (tid >> 3)) * (long)K + chOff;
    const unsigned char* bSrc = B8 + (n0 + (tid >> 3)) * (long)K + chOff;

    // ---- per-lane ds_read chunk offsets (swizzled) ----
    // k-half ks occupies chunks [ks*4, ks*4+4); lane's 32B run = chunks ks*4+2h,+1
    const int c0s = (((0 + 2*h + 0) ^ sw) << 4);
    const int c1s = (((0 + 2*h + 1) ^ sw) << 4);
    const int c2s = (((4 + 2*h + 0) ^ sw) << 4);
    const int c3s = (((4 + 2*h + 1) ^ sw) << 4);

    // frag row bases (row&7 == lrow&7 for all mt/nt since offsets are mult. of 8)
    int offA[4], offB[4];
#pragma unroll
    for (int mt = 0; mt < 4; ++mt) offA[mt] = (wr * 128 + mt * 32 + lrow) * BKB;
#pragma unroll
    for (int nt = 0; nt < 4; ++nt) offB[nt] = (wc * 128 + nt * 32 + lrow) * BKB;

    v16f acc[4][4];
#pragma unroll
    for (int i = 0; i < 4; ++i)
#pragma unroll
        for (int j = 0; j < 4; ++j)
#pragma unroll
            for (int e = 0; e < 16; ++e)
                acc[i][j][e] = 0.f;

#define MFMA(AV, BV, D) \
    D = __builtin_amdgcn_mfma_scale_f32_32x32x64_f8f6f4( \
        (AV), (BV), (D), 0, 0, 0, SCONE, 0, SCONE)

    // stage one 128B K-tile (A+B, 64 KB) into buffer `slot`: 16 loads/thread
    auto stage = [&](long ktB, int slot) {
        unsigned char* al = AsB + slot * TILE_BYTES + tid * 16;
        unsigned char* bl = BsB + slot * TILE_BYTES + tid * 16;
        const unsigned char* ag = aSrc + ktB;
        const unsigned char* bg = bSrc + ktB;
#pragma unroll
        for (int j = 0; j < 8; ++j)
            async_copy16(ag + j * rowStep, al + j * 4096);
#pragma unroll
        for (int j = 0; j < 8; ++j)
            async_copy16(bg + j * rowStep, bl + j * 4096);
    };

    const int NT = K / BKB;                  // 32
    stage(0, 0);

    for (int t = 0; t < NT; ++t) {
        if (t + 1 < NT) {
            stage((long)(t + 1) * BKB, (t + 1) & 1);          // 32 outstanding
            asm volatile("s_waitcnt vmcnt(16)" ::: "memory"); // tile t done; 16 in flight
        } else {
            asm volatile("s_waitcnt vmcnt(0)" ::: "memory");
        }
        __builtin_amdgcn_s_barrier();        // buf[t&1] ready block-wide

        const unsigned char* Ab = AsB + (t & 1) * TILE_BYTES;
        const unsigned char* Bb = BsB + (t & 1) * TILE_BYTES;

        // ---- k-half 0 ----
        {
            v8i a[4], b[4];
#pragma unroll
            for (int mt = 0; mt < 4; ++mt) a[mt] = ld32(Ab + offA[mt], c0s, c1s);
#pragma unroll
            for (int nt = 0; nt < 4; ++nt) b[nt] = ld32(Bb + offB[nt], c0s, c1s);
#pragma unroll
            for (int mt = 0; mt < 4; ++mt)
#pragma unroll
                for (int nt = 0; nt < 4; ++nt)
                    MFMA(a[mt], b[nt], acc[mt][nt]);
        }
        // ---- k-half 1 ----
        {
            v8i a[4], b[4];
#pragma unroll
            for (int mt = 0; mt < 4; ++mt) a[mt] = ld32(Ab + offA[mt], c2s, c3s);
#pragma unroll
            for (int nt = 0; nt < 4; ++nt) b[nt] = ld32(Bb + offB[nt], c2s, c3s);
#pragma unroll
            for (int mt = 0; mt < 4; ++mt)
#pragma unroll
                for (int nt = 0; nt < 4; ++nt)
                    MFMA(a[mt], b[nt], acc[mt][nt]);
        }

        __builtin_amdgcn_sched_barrier(0);   // keep step body above barrier-2
        __builtin_amdgcn_s_barrier();        // reads done: buf[(t+1)&1] writable
    }
#undef MFMA

    // ---- epilogue: 32x32 C/D layout: col = l&31, row = (reg&3) + 8*(reg>>2) + 4*h ----
    const float s = is_p[0] * ws_p[0];
#pragma unroll
    for (int mt = 0; mt < 4; ++mt)
#pragma unroll
        for (int nt = 0; nt < 4; ++nt) {
            const long cc = n0 + wc * 128 + nt * 32 + lrow;
            const float bv = bias[cc];
            float* dst = C + (m0 + wr * 128 + mt * 32 + h * 4) * (long)N + cc;
#pragma unroll
            for (int g = 0; g < 4; ++g)
#pragma unroll
                for (int r = 0; r < 4; ++r)
                    dst[(long)(g * 8 + r) * N] = acc[mt][nt][g * 4 + r] * s + bv;
        }
}

extern "C" void kernel_launch(void* const* d_in, const int* in_sizes, int n_in,
                              void* d_out, int out_size, void* d_ws, size_t ws_size,
                              hipStream_t stream)
{
    const float* X    = (const float*)d_in[0];   // [M,K] f32
    const float* Wf   = (const float*)d_in[1];   // [K,N] f32 (fp8-grid values)
    const float* bias = (const float*)d_in[2];   // [N] f32
    const float* wsc  = (const float*)d_in[3];   // weight_scale
    const float* isc  = (const float*)d_in[4];   // input_scale
    float* out = (float*)d_out;

    const int N = in_sizes[2];
    const int K = in_sizes[1] / N;
    const int M = in_sizes[0] / K;

    unsigned char* A8 = (unsigned char*)d_ws;            // M*K bytes
    unsigned char* B8 = A8 + (size_t)M * K;              // N*K bytes

    // 1) input quant
    quant_x_kernel<<<dim3((unsigned)((long)M * K / 4 / 256)), 256, 0, stream>>>(
        X, isc, (unsigned int*)A8);

    // 2) weight quant + transpose (LDS transpose, coalesced)
    quant_wT_kernel<<<dim3(K / 64, N / 64), 256, 0, stream>>>(Wf, B8, K, N);

    // 3) GEMM + scale + bias (MX-scaled fp8, fat-wave schedule)
    fp8_gemm_kernel<<<dim3(N / BN, M / BM), 256, 0, stream>>>(
        A8, B8, bias, wsc, isc, out, M, N, K);
}